// Round 7
// baseline (316.222 us; speedup 1.0000x reference)
//
#include <hip/hip_runtime.h>

// ---------------------------------------------------------------------------
// Algebra: emb = nd ⊙ (Â (ns ⊙ (feats@Wc + bc))) + b_gcn
//        = nd ⊙ ( g@Wc + h·bcᵀ ) + b_gcn     with g = Â(ns⊙feats), h = Â ns
// (Â = adjacency-by-dst incl. self loops; Wc = W_aff@W_gcn, bc = b_aff@W_gcn)
// Gather in F=128 feature space. pred MLP linear => weights = u1[s]+u2[o]+bd.
//
// R1: multi-block scan. 663→543. R2: bcomb split-K. 543→441.
// R3: bucket-partition CSR (no per-edge global atomics). 441→398.
// R4: gather unroll + atomic-free degrees. 398→365.
// R5: 16B/lane gather + partition fusions. 365→355.
// R6: 18→11 dispatches + sgemm split-K. 355→315. Top-5 = harness fills.
// R7: gcn_gemm BN=512/block (A-tile persistent in LDS, 4 col-tiles looped):
// u-dots complete in-block -> LDS reduce + plain stores (kills 400K device
// atomics, 12.8MB WRITE) and g16 fetched 1x not 4x (-38MB). sgemm+prep1
// fused. Pred ~290 µs.
// ---------------------------------------------------------------------------

typedef float f32x4 __attribute__((ext_vector_type(4)));
typedef short s16x8 __attribute__((ext_vector_type(8)));

__device__ __forceinline__ unsigned short f2bf(float f) {
    unsigned u = __float_as_uint(f);
    unsigned r = (u + 0x7FFFu + ((u >> 16) & 1u)) >> 16;
    return (unsigned short)r;
}

__device__ __forceinline__ void async_ld16(const void* g, void* lds) {
    __builtin_amdgcn_global_load_lds(
        (const __attribute__((address_space(1))) unsigned int*)g,
        (__attribute__((address_space(3))) unsigned int*)lds,
        16, 0, 0);
}

// ---------------------------------------------------------------------------
// One kernel replaces memsets: g16 pad rows, h pad, bucket hists.
// ---------------------------------------------------------------------------
__global__ __launch_bounds__(256) void init_kernel(
    unsigned* __restrict__ gpad, int nG,
    float* __restrict__ hpad, int nH, int* __restrict__ bh, int nB) {
    const int stride = gridDim.x * blockDim.x;
    const int i0 = blockIdx.x * blockDim.x + threadIdx.x;
    for (int i = i0; i < nG; i += stride) gpad[i] = 0u;
    for (int i = i0; i < nH; i += stride) hpad[i] = 0.f;
    for (int i = i0; i < nB; i += stride) bh[i] = 0;
}

// ---------------------------------------------------------------------------
// Bucket histograms of src>>8 and dst>>8 (LDS-aggregated, per-block flush).
// ---------------------------------------------------------------------------
__global__ __launch_bounds__(256) void hist2_kernel(
    const int* __restrict__ src, const int* __restrict__ dst,
    int* __restrict__ bhist_src, int* __restrict__ bhist_dst, int E) {
    __shared__ int lhs[256], lhd[256];
    lhs[threadIdx.x] = 0;
    lhd[threadIdx.x] = 0;
    __syncthreads();
    const int stride = gridDim.x * blockDim.x;
    for (int e = blockIdx.x * blockDim.x + threadIdx.x; e < E; e += stride) {
        atomicAdd(&lhs[src[e] >> 8], 1);
        atomicAdd(&lhd[dst[e] >> 8], 1);
    }
    __syncthreads();
    int cs = lhs[threadIdx.x], cd = lhd[threadIdx.x];
    if (cs > 0) atomicAdd(&bhist_src[threadIdx.x], cs);
    if (cd > 0) atomicAdd(&bhist_dst[threadIdx.x], cd);
}

// Exclusive scans of both bucket histograms -> bases + cursors. 1 block.
__global__ void bscan2_kernel(const int* __restrict__ bhist_src, const int* __restrict__ bhist_dst,
                              int* __restrict__ sbbase, int* __restrict__ sbcursor,
                              int* __restrict__ dbbase, int* __restrict__ dbcursor,
                              int nbuk, int E) {
    __shared__ int sv[256];
    const int tid = threadIdx.x;

    int c = (tid < nbuk) ? bhist_src[tid] : 0;
    sv[tid] = c;
    __syncthreads();
    for (int st = 1; st < 256; st <<= 1) {
        int t = (tid >= st) ? sv[tid - st] : 0;
        __syncthreads();
        sv[tid] += t;
        __syncthreads();
    }
    if (tid < nbuk) { int ex = sv[tid] - c; sbbase[tid] = ex; sbcursor[tid] = ex; }
    if (tid == 0) sbbase[nbuk] = E;
    __syncthreads();

    c = (tid < nbuk) ? bhist_dst[tid] : 0;
    sv[tid] = c;
    __syncthreads();
    for (int st = 1; st < 256; st <<= 1) {
        int t = (tid >= st) ? sv[tid - st] : 0;
        __syncthreads();
        sv[tid] += t;
        __syncthreads();
    }
    if (tid < nbuk) { int ex = sv[tid] - c; dbbase[tid] = ex; dbcursor[tid] = ex; }
    if (tid == 0) dbbase[nbuk] = E;
}

// ---------------------------------------------------------------------------
// Fused partition: one read of (src,dst); phase A sorts (dst,src) pairs by
// dst-bucket, phase B sorts src by src-bucket — LDS counting sorts, coalesced
// run writes, one cursor reservation per (block,bucket).
// ---------------------------------------------------------------------------
#define PCH 4096
__global__ __launch_bounds__(256) void fused_partition_kernel(
    const int* __restrict__ src, const int* __restrict__ dst,
    int* __restrict__ dcursor, unsigned long long* __restrict__ pairs,
    int* __restrict__ scursor, int* __restrict__ ssorted,
    int E, int nbuk) {
    __shared__ int lhist[256];
    __shared__ int lbase[256];
    __shared__ int gbase[256];
    __shared__ int scanv[256];
    __shared__ unsigned long long lpair[PCH];   // 32 KB (reused as int in B)
    __shared__ unsigned char lbid[PCH];

    const int tid = threadIdx.x;
    const int c0 = blockIdx.x * PCH;
    int cnt = E - c0; if (cnt > PCH) cnt = PCH;

    int dv[16], sv[16], rk[16];

    // ---- phase A: (dst,src) by dst-bucket ----
    lhist[tid] = 0;
    __syncthreads();
#pragma unroll
    for (int q = 0; q < 16; ++q) {
        int e = c0 + q * 256 + tid;
        if (e < E) {
            int d = dst[e];
            dv[q] = d;
            sv[q] = src[e];
            rk[q] = atomicAdd(&lhist[d >> 8], 1);
        } else {
            dv[q] = -1;
            sv[q] = -1;
        }
    }
    __syncthreads();

    int c = lhist[tid];
    scanv[tid] = c;
    __syncthreads();
    for (int st = 1; st < 256; st <<= 1) {
        int t = (tid >= st) ? scanv[tid - st] : 0;
        __syncthreads();
        scanv[tid] += t;
        __syncthreads();
    }
    lbase[tid] = scanv[tid] - c;
    if (tid < nbuk && c > 0) gbase[tid] = atomicAdd(&dcursor[tid], c);
    __syncthreads();

#pragma unroll
    for (int q = 0; q < 16; ++q) {
        if (dv[q] >= 0) {
            int b = dv[q] >> 8;
            int slot = lbase[b] + rk[q];
            lpair[slot] = ((unsigned long long)(unsigned)dv[q] << 32) | (unsigned)sv[q];
            lbid[slot] = (unsigned char)b;
        }
    }
    __syncthreads();

    for (int i = tid; i < cnt; i += 256) {
        int b = lbid[i];
        pairs[(long)gbase[b] + (i - lbase[b])] = lpair[i];
    }
    __syncthreads();

    // ---- phase B: src by src-bucket (reuse LDS) ----
    int* lval = (int*)lpair;
    lhist[tid] = 0;
    __syncthreads();
#pragma unroll
    for (int q = 0; q < 16; ++q) {
        if (sv[q] >= 0) rk[q] = atomicAdd(&lhist[sv[q] >> 8], 1);
    }
    __syncthreads();

    c = lhist[tid];
    scanv[tid] = c;
    __syncthreads();
    for (int st = 1; st < 256; st <<= 1) {
        int t = (tid >= st) ? scanv[tid - st] : 0;
        __syncthreads();
        scanv[tid] += t;
        __syncthreads();
    }
    lbase[tid] = scanv[tid] - c;
    if (tid < nbuk && c > 0) gbase[tid] = atomicAdd(&scursor[tid], c);
    __syncthreads();

#pragma unroll
    for (int q = 0; q < 16; ++q) {
        if (sv[q] >= 0) {
            int b = sv[q] >> 8;
            int slot = lbase[b] + rk[q];
            lval[slot] = sv[q];
            lbid[slot] = (unsigned char)b;
        }
    }
    __syncthreads();

    for (int i = tid; i < cnt; i += 256) {
        int b = lbid[i];
        ssorted[(long)gbase[b] + (i - lbase[b])] = lval[i];
    }
}

// ---------------------------------------------------------------------------
// Per-bucket finalize: CSR (row_ptr, nd, csr_src) + out-degree -> ns, AND
// conv_feats for the bucket's 256 nodes (fs16 = bf16(ns ⊙ feats)).
// ---------------------------------------------------------------------------
__global__ __launch_bounds__(256) void bucket_finalize_kernel(
    const unsigned long long* __restrict__ pairs, const int* __restrict__ dbbase,
    const int* __restrict__ ssorted, const int* __restrict__ sbbase,
    const float* __restrict__ feats,
    int* __restrict__ row_ptr, float* __restrict__ ndv,
    int* __restrict__ csr_src, float* __restrict__ ns,
    unsigned short* __restrict__ fs16, int N) {
    __shared__ int hist[256];
    __shared__ int scanv[256];
    __shared__ int lcur[256];
    __shared__ float nsv[256];
    const int tid = threadIdx.x;
    const int b = blockIdx.x;
    const int node = b * 256 + tid;

    // ---- CSR for dst-bucket b ----
    const int e0 = dbbase[b], e1 = dbbase[b + 1];
    hist[tid] = 0;
    __syncthreads();
    for (int e = e0 + tid; e < e1; e += 256) {
        int d = (int)(pairs[e] >> 32);
        atomicAdd(&hist[d & 255], 1);
    }
    __syncthreads();

    int c = hist[tid];
    scanv[tid] = c;
    __syncthreads();
    for (int st = 1; st < 256; st <<= 1) {
        int t = (tid >= st) ? scanv[tid - st] : 0;
        __syncthreads();
        scanv[tid] += t;
        __syncthreads();
    }
    int excl = scanv[tid] - c;
    if (node < N) {
        row_ptr[node] = e0 + excl;
        ndv[node] = rsqrtf((float)(c + 1));
    }
    if (node == N) row_ptr[N] = e0 + excl;
    lcur[tid] = excl;
    __syncthreads();

    for (int e = e0 + tid; e < e1; e += 256) {
        unsigned long long pr = pairs[e];
        int d = (int)(pr >> 32);
        int r = atomicAdd(&lcur[d & 255], 1);
        csr_src[e0 + r] = (int)(pr & 0xFFFFFFFFu);
    }

    // ---- out-degree histogram for src-bucket b -> ns ----
    __syncthreads();
    hist[tid] = 0;
    __syncthreads();
    const int s0 = sbbase[b], s1 = sbbase[b + 1];
    for (int e = s0 + tid; e < s1; e += 256) atomicAdd(&hist[ssorted[e] & 255], 1);
    __syncthreads();
    float nsval = rsqrtf((float)(hist[tid] + 1));
    nsv[tid] = nsval;
    if (node < N) ns[node] = nsval;
    __syncthreads();

    // ---- conv_feats for nodes [b*256, b*256+256): 16 rows/iter
    for (int r0 = 0; r0 < 256; r0 += 16) {
        int r = r0 + (tid >> 4);
        int nn = b * 256 + r;
        if (nn >= N) break;
        int cq = (tid & 15) * 8;
        float s = nsv[r];
        const float* pf = feats + (long)nn * 128 + cq;
        float4 a = *reinterpret_cast<const float4*>(pf);
        float4 d2 = *reinterpret_cast<const float4*>(pf + 4);
        uint4 o;
        o.x = (unsigned)f2bf(a.x * s) | ((unsigned)f2bf(a.y * s) << 16);
        o.y = (unsigned)f2bf(a.z * s) | ((unsigned)f2bf(a.w * s) << 16);
        o.z = (unsigned)f2bf(d2.x * s) | ((unsigned)f2bf(d2.y * s) << 16);
        o.w = (unsigned)f2bf(d2.z * s) | ((unsigned)f2bf(d2.w * s) << 16);
        *reinterpret_cast<uint4*>(fs16 + (long)nn * 128 + cq) = o;
    }
}

// ---------------------------------------------------------------------------
// dense_prep: branched fusion of {sgemm split-K | bcomb partials | vcomb |
// bias_dot} — all independent work, one launch.
// sgemm: Wcp[z] = W_aff @ W_gcn over K-chunk z (chunks of 128).
// ---------------------------------------------------------------------------
__global__ __launch_bounds__(256) void dense_prep_kernel(
    const float* __restrict__ A, int lda,      // W_aff [F][D... lda=D? no: W_aff is F x D(cols=D)? A=W_aff [128][500]
    const float* __restrict__ B, int ldb,      // W_gcn [500][500]
    float* __restrict__ Cp, int ldc, int M, int Nn, int K,
    const float* __restrict__ b_aff, float* __restrict__ part,
    const float* __restrict__ Win, const float* __restrict__ wout,
    float* __restrict__ v,
    const float* __restrict__ b_in, const float* __restrict__ b_out,
    float* __restrict__ bdot,
    int D, int PD, int gxn, int gyn, int NBsg, int NBbc, int NBv, int nbper) {
    __shared__ __align__(16) float As[16][68];
    __shared__ __align__(16) float Bs[16][68];
    const int blk = blockIdx.x;
    const int tid = threadIdx.x;

    if (blk < NBsg) {
        // ---- sgemm split-K block ----
        const int gx = blk % gxn;
        const int gy = (blk / gxn) % gyn;
        const int gz = blk / (gxn * gyn);
        const int tx = tid & 15, ty = tid >> 4;
        const int row0 = gx * 64;
        const int col0 = gy * 64;
        const int kbeg = gz * 128;
        int kend = kbeg + 128; if (kend > K) kend = K;
        float* C = Cp + (long)gz * M * ldc;

        const int a_row = tid >> 2;
        const int a_k   = (tid & 3) * 4;
        const int b_k   = tid >> 4;
        const int b_c   = (tid & 15) * 4;

        float acc[4][4] = {};

        for (int k0 = kbeg; k0 < kend; k0 += 16) {
            float4 av = make_float4(0.f, 0.f, 0.f, 0.f);
            {
                int gr = row0 + a_row;
                int gk = k0 + a_k;
                if (gr < M) {
                    if (gk + 3 < kend) {
                        av = *reinterpret_cast<const float4*>(&A[(long)gr * lda + gk]);
                    } else {
                        float t0 = (gk + 0 < kend) ? A[(long)gr * lda + gk + 0] : 0.f;
                        float t1 = (gk + 1 < kend) ? A[(long)gr * lda + gk + 1] : 0.f;
                        float t2 = (gk + 2 < kend) ? A[(long)gr * lda + gk + 2] : 0.f;
                        float t3 = (gk + 3 < kend) ? A[(long)gr * lda + gk + 3] : 0.f;
                        av = make_float4(t0, t1, t2, t3);
                    }
                }
            }
            float4 bv = make_float4(0.f, 0.f, 0.f, 0.f);
            {
                int gk = k0 + b_k;
                int gc = col0 + b_c;
                if (gk < kend) {
                    if (gc + 3 < Nn) {
                        bv = *reinterpret_cast<const float4*>(&B[(long)gk * ldb + gc]);
                    } else {
                        float t0 = (gc + 0 < Nn) ? B[(long)gk * ldb + gc + 0] : 0.f;
                        float t1 = (gc + 1 < Nn) ? B[(long)gk * ldb + gc + 1] : 0.f;
                        float t2 = (gc + 2 < Nn) ? B[(long)gk * ldb + gc + 2] : 0.f;
                        float t3 = (gc + 3 < Nn) ? B[(long)gk * ldb + gc + 3] : 0.f;
                        bv = make_float4(t0, t1, t2, t3);
                    }
                }
            }
            __syncthreads();
            As[a_k + 0][a_row] = av.x;
            As[a_k + 1][a_row] = av.y;
            As[a_k + 2][a_row] = av.z;
            As[a_k + 3][a_row] = av.w;
            *reinterpret_cast<float4*>(&Bs[b_k][b_c]) = bv;
            __syncthreads();

#pragma unroll
            for (int k = 0; k < 16; ++k) {
                const float4 a = *reinterpret_cast<const float4*>(&As[k][ty * 4]);
                const float4 b2 = *reinterpret_cast<const float4*>(&Bs[k][tx * 4]);
                const float avv[4] = {a.x, a.y, a.z, a.w};
                const float bvv[4] = {b2.x, b2.y, b2.z, b2.w};
#pragma unroll
                for (int i = 0; i < 4; ++i)
#pragma unroll
                    for (int j = 0; j < 4; ++j)
                        acc[i][j] = fmaf(avv[i], bvv[j], acc[i][j]);
            }
        }

#pragma unroll
        for (int i = 0; i < 4; ++i) {
            int r = row0 + ty * 4 + i;
            if (r >= M) continue;
#pragma unroll
            for (int j = 0; j < 4; ++j) {
                int cc = col0 + tx * 4 + j;
                if (cc < Nn) C[(long)r * ldc + cc] = acc[i][j];
            }
        }
    } else if (blk < NBsg + NBbc) {
        // ---- bcomb partial: chunk cch covers k in [8cch, min(8cch+8,D)) ----
        int b2 = blk - NBsg;
        int nblk = b2 % nbper;
        int cch = b2 / nbper;
        int n = nblk * 256 + tid;
        if (n >= PD) return;
        float s = 0.f;
        if (n < D) {
            int k0 = cch * 8;
            int k1 = k0 + 8; if (k1 > D) k1 = D;
            for (int k = k0; k < k1; ++k) s = fmaf(b_aff[k], B[(long)k * ldb + n], s);
        }
        part[(long)cch * PD + n] = s;
    } else if (blk < NBsg + NBbc + NBv) {
        // ---- vcomb: one wave per row k ----
        int k = (blk - NBsg - NBbc) * 4 + (tid >> 6);
        int lane = tid & 63;
        if (k >= 2 * D) return;
        float s = 0.f;
        for (int cc = lane; cc < D; cc += 64) s = fmaf(Win[(long)k * D + cc], wout[cc], s);
#pragma unroll
        for (int m = 32; m > 0; m >>= 1) s += __shfl_down(s, m);
        if (lane == 0) v[k] = s;
    } else {
        // ---- bias_dot ----
        float* sm = &As[0][0];
        float s = 0.f;
        for (int cc = tid; cc < D; cc += 256) s = fmaf(b_in[cc], wout[cc], s);
        sm[tid] = s;
        __syncthreads();
        for (int st = 128; st > 0; st >>= 1) {
            if (tid < st) sm[tid] += sm[tid + st];
            __syncthreads();
        }
        if (tid == 0) bdot[0] = sm[0] + b_out[0];
    }
}

// ---------------------------------------------------------------------------
// conv_Bt (+ fused pad): blocks [0,32): Bt[n][k] = bf16(Σ_z Wcp[z][k][n]);
// last blocks: bcp/bgp/v1p/v2p pads (bcp reduced from bcomb partials).
// ---------------------------------------------------------------------------
__global__ __launch_bounds__(256) void convBt_pad_kernel(
    const float* __restrict__ Wcp, unsigned short* __restrict__ Bt,
    const float* __restrict__ part, const float* __restrict__ b_gcn,
    const float* __restrict__ v, float* __restrict__ bcp,
    float* __restrict__ bgp, float* __restrict__ v1p, float* __restrict__ v2p,
    int D, int PD, int NC, int F, int nConvBlk) {
    const int b = blockIdx.x;
    const int tid = threadIdx.x;
    if (b < nConvBlk) {
        int idx = b * 256 + tid;
        if (idx >= PD * 16) return;
        int n = idx >> 4;
        int k8 = (idx & 15) * 8;
        uint4 o = make_uint4(0, 0, 0, 0);
        if (n < D) {
            unsigned short t[8];
            const long FD = (long)F * D;
#pragma unroll
            for (int q = 0; q < 8; ++q) {
                long off = (long)(k8 + q) * D + n;
                float val = Wcp[off] + Wcp[FD + off] + Wcp[2 * FD + off] + Wcp[3 * FD + off];
                t[q] = f2bf(val);
            }
            o.x = (unsigned)t[0] | ((unsigned)t[1] << 16);
            o.y = (unsigned)t[2] | ((unsigned)t[3] << 16);
            o.z = (unsigned)t[4] | ((unsigned)t[5] << 16);
            o.w = (unsigned)t[6] | ((unsigned)t[7] << 16);
        }
        *reinterpret_cast<uint4*>(Bt + (long)n * 128 + k8) = o;
    } else {
        int i = (b - nConvBlk) * 256 + tid;
        if (i < PD) {
            float s = 0.f;
            for (int c = 0; c < NC; ++c) s += part[(long)c * PD + i];
            bcp[i] = s;
            bgp[i] = (i < D) ? b_gcn[i] : 0.f;
            v1p[i] = (i < D) ? v[i] : 0.f;
            v2p[i] = (i < D) ? v[D + i] : 0.f;
        }
    }
}

// ---------------------------------------------------------------------------
// Feature-space CSR gather, wave per node, 16B/lane loads.
//   g16[d] = bf16( Σ_{s∈in(d)} fs16[s] + fs16[d] ),  h[d] = Σ ns[s] + ns[d]
// ---------------------------------------------------------------------------
__global__ __launch_bounds__(256) void gather_feats_kernel(
    const unsigned short* __restrict__ fs16, const int* __restrict__ csr_src,
    const int* __restrict__ row_ptr, const float* __restrict__ ns,
    unsigned short* __restrict__ g16, float* __restrict__ h, int N) {
    int d = blockIdx.x * 4 + (threadIdx.x >> 6);
    int lane = threadIdx.x & 63;
    if (d >= N) return;
    const int g = lane >> 4;      // neighbor slot within quad
    const int fl = lane & 15;     // feature slot (8 feats)

    float a[8] = {0.f, 0.f, 0.f, 0.f, 0.f, 0.f, 0.f, 0.f};
    float hacc = 0.f;

    const int beg = row_ptr[d], end = row_ptr[d + 1];
    for (int j0 = beg; j0 < end; j0 += 64) {
        int cnt = end - j0;
        if (cnt > 64) cnt = 64;
        int s = (lane < cnt) ? csr_src[j0 + lane] : 0;
        if (lane < cnt) hacc += ns[s];
        for (int k = 0; k < cnt; k += 8) {
            int k0 = k + g, k1 = k + 4 + g;
            int i0 = __shfl(s, k0 & 63);
            int i1 = __shfl(s, k1 & 63);
            uint4 v0 = make_uint4(0u, 0u, 0u, 0u), v1 = make_uint4(0u, 0u, 0u, 0u);
            if (k0 < cnt) v0 = *reinterpret_cast<const uint4*>(fs16 + (long)i0 * 128 + fl * 8);
            if (k1 < cnt) v1 = *reinterpret_cast<const uint4*>(fs16 + (long)i1 * 128 + fl * 8);
            a[0] += __uint_as_float(v0.x << 16); a[1] += __uint_as_float(v0.x & 0xFFFF0000u);
            a[2] += __uint_as_float(v0.y << 16); a[3] += __uint_as_float(v0.y & 0xFFFF0000u);
            a[4] += __uint_as_float(v0.z << 16); a[5] += __uint_as_float(v0.z & 0xFFFF0000u);
            a[6] += __uint_as_float(v0.w << 16); a[7] += __uint_as_float(v0.w & 0xFFFF0000u);
            a[0] += __uint_as_float(v1.x << 16); a[1] += __uint_as_float(v1.x & 0xFFFF0000u);
            a[2] += __uint_as_float(v1.y << 16); a[3] += __uint_as_float(v1.y & 0xFFFF0000u);
            a[4] += __uint_as_float(v1.z << 16); a[5] += __uint_as_float(v1.z & 0xFFFF0000u);
            a[6] += __uint_as_float(v1.w << 16); a[7] += __uint_as_float(v1.w & 0xFFFF0000u);
        }
    }

#pragma unroll
    for (int r = 0; r < 8; ++r) {
        a[r] += __shfl_xor(a[r], 16);
        a[r] += __shfl_xor(a[r], 32);
    }
    {
        uint4 sv4 = *reinterpret_cast<const uint4*>(fs16 + (long)d * 128 + fl * 8);
        a[0] += __uint_as_float(sv4.x << 16); a[1] += __uint_as_float(sv4.x & 0xFFFF0000u);
        a[2] += __uint_as_float(sv4.y << 16); a[3] += __uint_as_float(sv4.y & 0xFFFF0000u);
        a[4] += __uint_as_float(sv4.z << 16); a[5] += __uint_as_float(sv4.z & 0xFFFF0000u);
        a[6] += __uint_as_float(sv4.w << 16); a[7] += __uint_as_float(sv4.w & 0xFFFF0000u);
    }
#pragma unroll
    for (int m = 32; m > 0; m >>= 1) hacc += __shfl_xor(hacc, m);
    if (lane == 0) h[d] = hacc + ns[d];
    if (lane < 16) {
        uint4 o;
        o.x = (unsigned)f2bf(a[0]) | ((unsigned)f2bf(a[1]) << 16);
        o.y = (unsigned)f2bf(a[2]) | ((unsigned)f2bf(a[3]) << 16);
        o.z = (unsigned)f2bf(a[4]) | ((unsigned)f2bf(a[5]) << 16);
        o.w = (unsigned)f2bf(a[6]) | ((unsigned)f2bf(a[7]) << 16);
        *reinterpret_cast<uint4*>(g16 + (long)d * 128 + fl * 8) = o;
    }
}

// ---------------------------------------------------------------------------
// MFMA GEMM, BN=512/block: A-tile (128 rows x 128 K) persistent in LDS; loop
// 4 column tiles x 4 K-steps with 8KB B staging. emb finalize fused; u-dots
// complete in-block -> LDS reduce -> plain stores (no atomics).
// ---------------------------------------------------------------------------
__global__ __launch_bounds__(256) void gcn_gemm_kernel(
    const unsigned short* __restrict__ g16, const unsigned short* __restrict__ Bt,
    const float* __restrict__ h, const float* __restrict__ nd,
    const float* __restrict__ bcp, const float* __restrict__ bgp,
    const float* __restrict__ v1p, const float* __restrict__ v2p,
    float* __restrict__ emb, float* __restrict__ u1, float* __restrict__ u2,
    int M, int D) {

    __shared__ __align__(16) unsigned short As[128 * 128];   // 32 KB persistent
    __shared__ __align__(16) unsigned short Bs[128 * 32];    // 8 KB staging
    __shared__ float us1[128], us2[128];

    const int tid  = threadIdx.x;
    const int w    = tid >> 6;
    const int lane = tid & 63;
    const int row0 = blockIdx.x * 128;

    const int r0   = 2 * w * 16 + (lane >> 2);
    const int r1   = (2 * w + 1) * 16 + (lane >> 2);
    const int slot = lane & 3;
    const int c0   = slot ^ ((r0 >> 1) & 3);
    const int c1   = slot ^ ((r1 >> 1) & 3);

    const unsigned short* pA0 = g16 + (long)(row0 + r0) * 128 + c0 * 8;
    const unsigned short* pA1 = g16 + (long)(row0 + r1) * 128 + c1 * 8;

    unsigned short* dA0 = As + 2 * w * 512;
    unsigned short* dA1 = As + (2 * w + 1) * 512;
    unsigned short* dB0 = Bs + 2 * w * 512;
    unsigned short* dB1 = Bs + (2 * w + 1) * 512;

    // stage the full A tile: 4 k-chunks of [128 rows x 32 k]
#pragma unroll
    for (int kc = 0; kc < 4; ++kc) {
        async_ld16(pA0 + kc * 32, dA0 + kc * 4096);
        async_ld16(pA1 + kc * 32, dA1 + kc * 4096);
    }

    if (tid < 128) { us1[tid] = 0.f; us2[tid] = 0.f; }

    const int wrow = (w & 1) * 64;
    const int wcol = (w >> 1) * 64;
    const int lm = lane & 15, q = lane >> 4;

    float usum1[4][4], usum2[4][4];
#pragma unroll
    for (int i = 0; i < 4; ++i)
#pragma unroll
        for (int r = 0; r < 4; ++r) { usum1[i][r] = 0.f; usum2[i][r] = 0.f; }

    for (int ct = 0; ct < 4; ++ct) {
        const int col0 = ct * 128;
        const unsigned short* pB0 = Bt + (long)(col0 + r0) * 128 + c0 * 8;
        const unsigned short* pB1 = Bt + (long)(col0 + r1) * 128 + c1 * 8;

        f32x4 acc[4][4];
#pragma unroll
        for (int i = 0; i < 4; ++i)
#pragma unroll
            for (int j = 0; j < 4; ++j) acc[i][j] = (f32x4)0.f;

        for (int kc = 0; kc < 4; ++kc) {
            async_ld16(pB0 + kc * 32, dB0);
            async_ld16(pB1 + kc * 32, dB1);
            __syncthreads();

            s16x8 af[4], bf[4];
#pragma unroll
            for (int i = 0; i < 4; ++i) {
                int r = wrow + i * 16 + lm;
                int cs = q ^ ((r >> 1) & 3);
                af[i] = *reinterpret_cast<const s16x8*>(As + kc * 4096 + r * 32 + cs * 8);
                int n = wcol + i * 16 + lm;
                int cs2 = q ^ ((n >> 1) & 3);
                bf[i] = *reinterpret_cast<const s16x8*>(Bs + n * 32 + cs2 * 8);
            }
#pragma unroll
            for (int i = 0; i < 4; ++i)
#pragma unroll
                for (int j = 0; j < 4; ++j)
                    acc[i][j] = __builtin_amdgcn_mfma_f32_16x16x32_bf16(af[i], bf[j], acc[i][j], 0, 0, 0);
            __syncthreads();
        }

        // epilogue for this column tile
        float bcv[4], bgv[4], w1v[4], w2v[4];
        int colv[4];
#pragma unroll
        for (int j = 0; j < 4; ++j) {
            int cc = col0 + wcol + j * 16 + lm;
            colv[j] = cc;
            bcv[j] = bcp[cc];
            bgv[j] = bgp[cc];
            w1v[j] = v1p[cc];
            w2v[j] = v2p[cc];
        }
#pragma unroll
        for (int i = 0; i < 4; ++i) {
#pragma unroll
            for (int reg = 0; reg < 4; ++reg) {
                int row = row0 + wrow + i * 16 + q * 4 + reg;
                float hb = h[row];
                float sc = (row < M) ? nd[row] : 0.f;
                float s1 = 0.f, s2 = 0.f;
#pragma unroll
                for (int j = 0; j < 4; ++j) {
                    float o = fmaf(sc, acc[i][j][reg] + hb * bcv[j], bgv[j]);
                    if (row < M && colv[j] < D) emb[(long)row * D + colv[j]] = o;
                    s1 = fmaf(o, w1v[j], s1);
                    s2 = fmaf(o, w2v[j], s2);
                }
                usum1[i][reg] += s1;
                usum2[i][reg] += s2;
            }
        }
    }

    // reduce u-dot partials: across the 16 lm lanes, then across wave-columns
#pragma unroll
    for (int mask = 1; mask < 16; mask <<= 1)
#pragma unroll
        for (int i = 0; i < 4; ++i)
#pragma unroll
            for (int reg = 0; reg < 4; ++reg) {
                usum1[i][reg] += __shfl_xor(usum1[i][reg], mask);
                usum2[i][reg] += __shfl_xor(usum2[i][reg], mask);
            }
    if (lm == 0) {
#pragma unroll
        for (int i = 0; i < 4; ++i)
#pragma unroll
            for (int reg = 0; reg < 4; ++reg) {
                int lr = wrow + i * 16 + q * 4 + reg;
                atomicAdd(&us1[lr], usum1[i][reg]);   // LDS atomics (2 adds/row)
                atomicAdd(&us2[lr], usum2[i][reg]);
            }
    }
    __syncthreads();
    if (tid < 128) {
        int row = row0 + tid;
        if (row < M) {
            u1[row] = us1[tid];
            u2[row] = us2[tid];
        }
    }
}

// weights[r] = u1[trip[r,0]] + u2[trip[r,2]] + bias_dot
__global__ void weights_kernel(const int* __restrict__ trip, const float* __restrict__ u1,
                               const float* __restrict__ u2, const float* __restrict__ bdot,
                               float* __restrict__ w, int T) {
    int r = blockIdx.x * blockDim.x + threadIdx.x;
    if (r < T) {
        int s = trip[(long)r * 3 + 0];
        int o = trip[(long)r * 3 + 2];
        w[r] = u1[s] + u2[o] + bdot[0];
    }
}

// ---------------------------------------------------------------------------

extern "C" void kernel_launch(void* const* d_in, const int* in_sizes, int n_in,
                              void* d_out, int out_size, void* d_ws, size_t ws_size,
                              hipStream_t stream) {
    const float* feats      = (const float*)d_in[0];
    const float* W_aff      = (const float*)d_in[1];
    const float* b_aff      = (const float*)d_in[2];
    const float* W_gcn      = (const float*)d_in[3];
    const float* b_gcn      = (const float*)d_in[4];
    const float* W_pred_in  = (const float*)d_in[5];
    const float* b_pred_in  = (const float*)d_in[6];
    const float* W_pred_out = (const float*)d_in[7];
    const float* b_pred_out = (const float*)d_in[8];
    const int*   src        = (const int*)d_in[9];
    const int*   dst        = (const int*)d_in[10];
    const int*   trip       = (const int*)d_in[11];

    const int D = in_sizes[2];           // 500
    const int F = in_sizes[1] / D;       // 128
    const int N = in_sizes[0] / F;       // 50000
    const int E = in_sizes[9];           // 800000
    const int T = in_sizes[11] / 3;      // 200000

    const int PD = 512;
    const int GX = (N + 127) / 128;      // 391 row-blocks
    const int Mpad = GX * 128;           // 50048
    const int NC = (D + 7) / 8;          // bcomb split-K chunks (63)
    const int NBUK = (N >> 8) + 1;       // 196 buckets of 256 nodes
    const int KS = 4;                    // sgemm split-K chunks of 128

    float* weights = (float*)d_out;          // [T]
    float* emb     = (float*)d_out + T;      // [N*D]

    // workspace layout (16B-aligned chunks first)
    char* p = (char*)d_ws;
    unsigned short* fs16 = (unsigned short*)p;  p += (size_t)N * 128 * 2;        // 12.8 MB
    unsigned short* g16  = (unsigned short*)p;  p += (size_t)Mpad * 128 * 2;     // 12.8 MB
    unsigned long long* pairs = (unsigned long long*)p; p += (size_t)E * 8;      // 6.4 MB
    int* ssorted = (int*)p;  p += (size_t)E * 4;                                 // 3.2 MB
    unsigned short* Bt   = (unsigned short*)p;  p += (size_t)PD * 128 * 2;       // 128 KB
    float* Wcp  = (float*)p;  p += (size_t)KS * F * D * 4;                       // 1 MB (split-K partials)
    float* bparts = (float*)p;  p += (size_t)64 * PD * 4;                        // 128 KB
    float* bcp  = (float*)p;  p += PD * 4;
    float* bgp  = (float*)p;  p += PD * 4;
    float* v1p  = (float*)p;  p += PD * 4;
    float* v2p  = (float*)p;  p += PD * 4;
    float* v    = (float*)p;  p += 1024 * 4;
    float* bdot = (float*)p;  p += 16;
    float* ns   = (float*)p;  p += (size_t)N * 4;
    float* nd   = (float*)p;  p += (size_t)N * 4;
    float* h    = (float*)p;  p += (size_t)Mpad * 4;
    float* u1   = (float*)p;  p += (size_t)N * 4;
    float* u2   = (float*)p;  p += (size_t)N * 4;
    int* bhist_src = (int*)p;  p += 256 * 4;     // bhist_src,bhist_dst contiguous
    int* bhist_dst = (int*)p;  p += 256 * 4;
    int* sbbase   = (int*)p;  p += 260 * 4;
    int* sbcursor = (int*)p;  p += 256 * 4;
    int* dbbase   = (int*)p;  p += 260 * 4;
    int* dbcursor = (int*)p;  p += 256 * 4;
    int* row_ptr = (int*)p;  p += (size_t)(N + 1) * 4;
    int* csr_src = (int*)p;  p += (size_t)E * 4;

    // init: g16 pad rows, h pad, bucket hists (u1/u2 now plain-stored)
    init_kernel<<<128, 256, 0, stream>>>(
        (unsigned*)(g16 + (size_t)N * 128), (Mpad - N) * 128 / 2,
        h + N, Mpad - N,
        bhist_src, 512);

    // graph prep: histograms -> scans -> fused partition -> finalize(+ns+conv)
    hist2_kernel<<<256, 256, 0, stream>>>(src, dst, bhist_src, bhist_dst, E);
    bscan2_kernel<<<1, 256, 0, stream>>>(bhist_src, bhist_dst, sbbase, sbcursor,
                                         dbbase, dbcursor, NBUK, E);
    fused_partition_kernel<<<(E + PCH - 1) / PCH, 256, 0, stream>>>(
        src, dst, dbcursor, pairs, sbcursor, ssorted, E, NBUK);
    bucket_finalize_kernel<<<NBUK, 256, 0, stream>>>(pairs, dbbase, ssorted, sbbase,
                                                     feats, row_ptr, nd, csr_src, ns,
                                                     fs16, N);

    // dense prep (one launch): sgemm split-K + bcomb partials + vcomb + bias
    {
        const int gxn = (F + 63) / 64;               // 2
        const int gyn = (D + 63) / 64;               // 8
        const int NBsg = gxn * gyn * KS;             // 64
        const int nbper = (PD + 255) / 256;          // 2
        const int NBbc = nbper * NC;                 // 126
        const int NBv = (2 * D + 3) / 4;             // 250
        dense_prep_kernel<<<NBsg + NBbc + NBv + 1, 256, 0, stream>>>(
            W_aff, D, W_gcn, D, Wcp, D, F, D, D,
            b_aff, bparts, W_pred_in, W_pred_out, v,
            b_pred_in, b_pred_out, bdot,
            D, PD, gxn, gyn, NBsg, NBbc, NBv, nbper);
    }
    {
        const int nConvBlk = (PD * 16 + 255) / 256;   // 32
        const int nPadBlk = (PD + 255) / 256;         // 2
        convBt_pad_kernel<<<nConvBlk + nPadBlk, 256, 0, stream>>>(
            Wcp, Bt, bparts, b_gcn, v, bcp, bgp, v1p, v2p, D, PD, NC, F, nConvBlk);
    }

    // feature-space gather: g16, h
    gather_feats_kernel<<<(N + 3) / 4, 256, 0, stream>>>(fs16, csr_src, row_ptr, ns, g16, h, N);

    // MFMA GEMM, BN=512/block: emb + u1/u2 (no atomics)
    gcn_gemm_kernel<<<GX, 256, 0, stream>>>(g16, Bt, h, nd, bcp, bgp, v1p, v2p,
                                            emb, u1, u2, N, D);

    // weights from per-node scalars
    weights_kernel<<<(T + 255) / 256, 256, 0, stream>>>(trip, u1, u2, bdot, weights, T);
}

// Round 8
// 310.007 us; speedup vs baseline: 1.0200x; 1.0200x over previous
//
#include <hip/hip_runtime.h>

// ---------------------------------------------------------------------------
// Algebra: emb = nd ⊙ (Â (ns ⊙ (feats@Wc + bc))) + b_gcn
//        = nd ⊙ ( g@Wc + h·bcᵀ ) + b_gcn     with g = Â(ns⊙feats), h = Â ns
// (Â = adjacency-by-dst incl. self loops; Wc = W_aff@W_gcn, bc = b_aff@W_gcn)
// Gather in F=128 feature space. pred MLP linear => weights = u1[s]+u2[o]+bd.
//
// R1: multi-block scan. 663→543. R2: bcomb split-K. 543→441.
// R3: bucket-partition CSR (no per-edge global atomics). 441→398.
// R4: gather unroll + atomic-free degrees. 398→365.
// R5: 16B/lane gather + partition fusions. 365→355.
// R6: 18→11 dispatches + sgemm split-K. 355→315.
// R7: BN=512 A-persistent gemm: killed atomics/refetch but occupancy 8%
// (391 blocks), flat 316. Lesson: don't starve the grid.
// R8: R6 geometry (grid 391x4, 16KB LDS, full occupancy) + atomic-free u-dots
// via per-(colblock,wavecol) partial stores u{1,2}part[8][Mpad] + ufold.
// Pred ~285 µs (gemm 62→~30).
// ---------------------------------------------------------------------------

typedef float f32x4 __attribute__((ext_vector_type(4)));
typedef short s16x8 __attribute__((ext_vector_type(8)));

__device__ __forceinline__ unsigned short f2bf(float f) {
    unsigned u = __float_as_uint(f);
    unsigned r = (u + 0x7FFFu + ((u >> 16) & 1u)) >> 16;
    return (unsigned short)r;
}

__device__ __forceinline__ void async_ld16(const void* g, void* lds) {
    __builtin_amdgcn_global_load_lds(
        (const __attribute__((address_space(1))) unsigned int*)g,
        (__attribute__((address_space(3))) unsigned int*)lds,
        16, 0, 0);
}

// ---------------------------------------------------------------------------
// One kernel replaces memsets: g16 pad rows, h pad, bucket hists.
// ---------------------------------------------------------------------------
__global__ __launch_bounds__(256) void init_kernel(
    unsigned* __restrict__ gpad, int nG,
    float* __restrict__ hpad, int nH, int* __restrict__ bh, int nB) {
    const int stride = gridDim.x * blockDim.x;
    const int i0 = blockIdx.x * blockDim.x + threadIdx.x;
    for (int i = i0; i < nG; i += stride) gpad[i] = 0u;
    for (int i = i0; i < nH; i += stride) hpad[i] = 0.f;
    for (int i = i0; i < nB; i += stride) bh[i] = 0;
}

// ---------------------------------------------------------------------------
// Bucket histograms of src>>8 and dst>>8 (LDS-aggregated, per-block flush).
// ---------------------------------------------------------------------------
__global__ __launch_bounds__(256) void hist2_kernel(
    const int* __restrict__ src, const int* __restrict__ dst,
    int* __restrict__ bhist_src, int* __restrict__ bhist_dst, int E) {
    __shared__ int lhs[256], lhd[256];
    lhs[threadIdx.x] = 0;
    lhd[threadIdx.x] = 0;
    __syncthreads();
    const int stride = gridDim.x * blockDim.x;
    for (int e = blockIdx.x * blockDim.x + threadIdx.x; e < E; e += stride) {
        atomicAdd(&lhs[src[e] >> 8], 1);
        atomicAdd(&lhd[dst[e] >> 8], 1);
    }
    __syncthreads();
    int cs = lhs[threadIdx.x], cd = lhd[threadIdx.x];
    if (cs > 0) atomicAdd(&bhist_src[threadIdx.x], cs);
    if (cd > 0) atomicAdd(&bhist_dst[threadIdx.x], cd);
}

// Exclusive scans of both bucket histograms -> bases + cursors. 1 block.
__global__ void bscan2_kernel(const int* __restrict__ bhist_src, const int* __restrict__ bhist_dst,
                              int* __restrict__ sbbase, int* __restrict__ sbcursor,
                              int* __restrict__ dbbase, int* __restrict__ dbcursor,
                              int nbuk, int E) {
    __shared__ int sv[256];
    const int tid = threadIdx.x;

    int c = (tid < nbuk) ? bhist_src[tid] : 0;
    sv[tid] = c;
    __syncthreads();
    for (int st = 1; st < 256; st <<= 1) {
        int t = (tid >= st) ? sv[tid - st] : 0;
        __syncthreads();
        sv[tid] += t;
        __syncthreads();
    }
    if (tid < nbuk) { int ex = sv[tid] - c; sbbase[tid] = ex; sbcursor[tid] = ex; }
    if (tid == 0) sbbase[nbuk] = E;
    __syncthreads();

    c = (tid < nbuk) ? bhist_dst[tid] : 0;
    sv[tid] = c;
    __syncthreads();
    for (int st = 1; st < 256; st <<= 1) {
        int t = (tid >= st) ? sv[tid - st] : 0;
        __syncthreads();
        sv[tid] += t;
        __syncthreads();
    }
    if (tid < nbuk) { int ex = sv[tid] - c; dbbase[tid] = ex; dbcursor[tid] = ex; }
    if (tid == 0) dbbase[nbuk] = E;
}

// ---------------------------------------------------------------------------
// Fused partition: one read of (src,dst); phase A sorts (dst,src) pairs by
// dst-bucket, phase B sorts src by src-bucket — LDS counting sorts, coalesced
// run writes, one cursor reservation per (block,bucket).
// ---------------------------------------------------------------------------
#define PCH 4096
__global__ __launch_bounds__(256) void fused_partition_kernel(
    const int* __restrict__ src, const int* __restrict__ dst,
    int* __restrict__ dcursor, unsigned long long* __restrict__ pairs,
    int* __restrict__ scursor, int* __restrict__ ssorted,
    int E, int nbuk) {
    __shared__ int lhist[256];
    __shared__ int lbase[256];
    __shared__ int gbase[256];
    __shared__ int scanv[256];
    __shared__ unsigned long long lpair[PCH];   // 32 KB (reused as int in B)
    __shared__ unsigned char lbid[PCH];

    const int tid = threadIdx.x;
    const int c0 = blockIdx.x * PCH;
    int cnt = E - c0; if (cnt > PCH) cnt = PCH;

    int dv[16], sv[16], rk[16];

    // ---- phase A: (dst,src) by dst-bucket ----
    lhist[tid] = 0;
    __syncthreads();
#pragma unroll
    for (int q = 0; q < 16; ++q) {
        int e = c0 + q * 256 + tid;
        if (e < E) {
            int d = dst[e];
            dv[q] = d;
            sv[q] = src[e];
            rk[q] = atomicAdd(&lhist[d >> 8], 1);
        } else {
            dv[q] = -1;
            sv[q] = -1;
        }
    }
    __syncthreads();

    int c = lhist[tid];
    scanv[tid] = c;
    __syncthreads();
    for (int st = 1; st < 256; st <<= 1) {
        int t = (tid >= st) ? scanv[tid - st] : 0;
        __syncthreads();
        scanv[tid] += t;
        __syncthreads();
    }
    lbase[tid] = scanv[tid] - c;
    if (tid < nbuk && c > 0) gbase[tid] = atomicAdd(&dcursor[tid], c);
    __syncthreads();

#pragma unroll
    for (int q = 0; q < 16; ++q) {
        if (dv[q] >= 0) {
            int b = dv[q] >> 8;
            int slot = lbase[b] + rk[q];
            lpair[slot] = ((unsigned long long)(unsigned)dv[q] << 32) | (unsigned)sv[q];
            lbid[slot] = (unsigned char)b;
        }
    }
    __syncthreads();

    for (int i = tid; i < cnt; i += 256) {
        int b = lbid[i];
        pairs[(long)gbase[b] + (i - lbase[b])] = lpair[i];
    }
    __syncthreads();

    // ---- phase B: src by src-bucket (reuse LDS) ----
    int* lval = (int*)lpair;
    lhist[tid] = 0;
    __syncthreads();
#pragma unroll
    for (int q = 0; q < 16; ++q) {
        if (sv[q] >= 0) rk[q] = atomicAdd(&lhist[sv[q] >> 8], 1);
    }
    __syncthreads();

    c = lhist[tid];
    scanv[tid] = c;
    __syncthreads();
    for (int st = 1; st < 256; st <<= 1) {
        int t = (tid >= st) ? scanv[tid - st] : 0;
        __syncthreads();
        scanv[tid] += t;
        __syncthreads();
    }
    lbase[tid] = scanv[tid] - c;
    if (tid < nbuk && c > 0) gbase[tid] = atomicAdd(&scursor[tid], c);
    __syncthreads();

#pragma unroll
    for (int q = 0; q < 16; ++q) {
        if (sv[q] >= 0) {
            int b = sv[q] >> 8;
            int slot = lbase[b] + rk[q];
            lval[slot] = sv[q];
            lbid[slot] = (unsigned char)b;
        }
    }
    __syncthreads();

    for (int i = tid; i < cnt; i += 256) {
        int b = lbid[i];
        ssorted[(long)gbase[b] + (i - lbase[b])] = lval[i];
    }
}

// ---------------------------------------------------------------------------
// Per-bucket finalize: CSR (row_ptr, nd, csr_src) + out-degree -> ns, AND
// conv_feats for the bucket's 256 nodes (fs16 = bf16(ns ⊙ feats)).
// ---------------------------------------------------------------------------
__global__ __launch_bounds__(256) void bucket_finalize_kernel(
    const unsigned long long* __restrict__ pairs, const int* __restrict__ dbbase,
    const int* __restrict__ ssorted, const int* __restrict__ sbbase,
    const float* __restrict__ feats,
    int* __restrict__ row_ptr, float* __restrict__ ndv,
    int* __restrict__ csr_src, float* __restrict__ ns,
    unsigned short* __restrict__ fs16, int N) {
    __shared__ int hist[256];
    __shared__ int scanv[256];
    __shared__ int lcur[256];
    __shared__ float nsv[256];
    const int tid = threadIdx.x;
    const int b = blockIdx.x;
    const int node = b * 256 + tid;

    // ---- CSR for dst-bucket b ----
    const int e0 = dbbase[b], e1 = dbbase[b + 1];
    hist[tid] = 0;
    __syncthreads();
    for (int e = e0 + tid; e < e1; e += 256) {
        int d = (int)(pairs[e] >> 32);
        atomicAdd(&hist[d & 255], 1);
    }
    __syncthreads();

    int c = hist[tid];
    scanv[tid] = c;
    __syncthreads();
    for (int st = 1; st < 256; st <<= 1) {
        int t = (tid >= st) ? scanv[tid - st] : 0;
        __syncthreads();
        scanv[tid] += t;
        __syncthreads();
    }
    int excl = scanv[tid] - c;
    if (node < N) {
        row_ptr[node] = e0 + excl;
        ndv[node] = rsqrtf((float)(c + 1));
    }
    if (node == N) row_ptr[N] = e0 + excl;
    lcur[tid] = excl;
    __syncthreads();

    for (int e = e0 + tid; e < e1; e += 256) {
        unsigned long long pr = pairs[e];
        int d = (int)(pr >> 32);
        int r = atomicAdd(&lcur[d & 255], 1);
        csr_src[e0 + r] = (int)(pr & 0xFFFFFFFFu);
    }

    // ---- out-degree histogram for src-bucket b -> ns ----
    __syncthreads();
    hist[tid] = 0;
    __syncthreads();
    const int s0 = sbbase[b], s1 = sbbase[b + 1];
    for (int e = s0 + tid; e < s1; e += 256) atomicAdd(&hist[ssorted[e] & 255], 1);
    __syncthreads();
    float nsval = rsqrtf((float)(hist[tid] + 1));
    nsv[tid] = nsval;
    if (node < N) ns[node] = nsval;
    __syncthreads();

    // ---- conv_feats for nodes [b*256, b*256+256): 16 rows/iter
    for (int r0 = 0; r0 < 256; r0 += 16) {
        int r = r0 + (tid >> 4);
        int nn = b * 256 + r;
        if (nn >= N) break;
        int cq = (tid & 15) * 8;
        float s = nsv[r];
        const float* pf = feats + (long)nn * 128 + cq;
        float4 a = *reinterpret_cast<const float4*>(pf);
        float4 d2 = *reinterpret_cast<const float4*>(pf + 4);
        uint4 o;
        o.x = (unsigned)f2bf(a.x * s) | ((unsigned)f2bf(a.y * s) << 16);
        o.y = (unsigned)f2bf(a.z * s) | ((unsigned)f2bf(a.w * s) << 16);
        o.z = (unsigned)f2bf(d2.x * s) | ((unsigned)f2bf(d2.y * s) << 16);
        o.w = (unsigned)f2bf(d2.z * s) | ((unsigned)f2bf(d2.w * s) << 16);
        *reinterpret_cast<uint4*>(fs16 + (long)nn * 128 + cq) = o;
    }
}

// ---------------------------------------------------------------------------
// dense_prep: branched fusion of {sgemm split-K | bcomb partials | vcomb |
// bias_dot} — all independent work, one launch.
// ---------------------------------------------------------------------------
__global__ __launch_bounds__(256) void dense_prep_kernel(
    const float* __restrict__ A, int lda,
    const float* __restrict__ B, int ldb,
    float* __restrict__ Cp, int ldc, int M, int Nn, int K,
    const float* __restrict__ b_aff, float* __restrict__ part,
    const float* __restrict__ Win, const float* __restrict__ wout,
    float* __restrict__ v,
    const float* __restrict__ b_in, const float* __restrict__ b_out,
    float* __restrict__ bdot,
    int D, int PD, int gxn, int gyn, int NBsg, int NBbc, int NBv, int nbper) {
    __shared__ __align__(16) float As[16][68];
    __shared__ __align__(16) float Bs[16][68];
    const int blk = blockIdx.x;
    const int tid = threadIdx.x;

    if (blk < NBsg) {
        const int gx = blk % gxn;
        const int gy = (blk / gxn) % gyn;
        const int gz = blk / (gxn * gyn);
        const int tx = tid & 15, ty = tid >> 4;
        const int row0 = gx * 64;
        const int col0 = gy * 64;
        const int kbeg = gz * 128;
        int kend = kbeg + 128; if (kend > K) kend = K;
        float* C = Cp + (long)gz * M * ldc;

        const int a_row = tid >> 2;
        const int a_k   = (tid & 3) * 4;
        const int b_k   = tid >> 4;
        const int b_c   = (tid & 15) * 4;

        float acc[4][4] = {};

        for (int k0 = kbeg; k0 < kend; k0 += 16) {
            float4 av = make_float4(0.f, 0.f, 0.f, 0.f);
            {
                int gr = row0 + a_row;
                int gk = k0 + a_k;
                if (gr < M) {
                    if (gk + 3 < kend) {
                        av = *reinterpret_cast<const float4*>(&A[(long)gr * lda + gk]);
                    } else {
                        float t0 = (gk + 0 < kend) ? A[(long)gr * lda + gk + 0] : 0.f;
                        float t1 = (gk + 1 < kend) ? A[(long)gr * lda + gk + 1] : 0.f;
                        float t2 = (gk + 2 < kend) ? A[(long)gr * lda + gk + 2] : 0.f;
                        float t3 = (gk + 3 < kend) ? A[(long)gr * lda + gk + 3] : 0.f;
                        av = make_float4(t0, t1, t2, t3);
                    }
                }
            }
            float4 bv = make_float4(0.f, 0.f, 0.f, 0.f);
            {
                int gk = k0 + b_k;
                int gc = col0 + b_c;
                if (gk < kend) {
                    if (gc + 3 < Nn) {
                        bv = *reinterpret_cast<const float4*>(&B[(long)gk * ldb + gc]);
                    } else {
                        float t0 = (gc + 0 < Nn) ? B[(long)gk * ldb + gc + 0] : 0.f;
                        float t1 = (gc + 1 < Nn) ? B[(long)gk * ldb + gc + 1] : 0.f;
                        float t2 = (gc + 2 < Nn) ? B[(long)gk * ldb + gc + 2] : 0.f;
                        float t3 = (gc + 3 < Nn) ? B[(long)gk * ldb + gc + 3] : 0.f;
                        bv = make_float4(t0, t1, t2, t3);
                    }
                }
            }
            __syncthreads();
            As[a_k + 0][a_row] = av.x;
            As[a_k + 1][a_row] = av.y;
            As[a_k + 2][a_row] = av.z;
            As[a_k + 3][a_row] = av.w;
            *reinterpret_cast<float4*>(&Bs[b_k][b_c]) = bv;
            __syncthreads();

#pragma unroll
            for (int k = 0; k < 16; ++k) {
                const float4 a = *reinterpret_cast<const float4*>(&As[k][ty * 4]);
                const float4 b2 = *reinterpret_cast<const float4*>(&Bs[k][tx * 4]);
                const float avv[4] = {a.x, a.y, a.z, a.w};
                const float bvv[4] = {b2.x, b2.y, b2.z, b2.w};
#pragma unroll
                for (int i = 0; i < 4; ++i)
#pragma unroll
                    for (int j = 0; j < 4; ++j)
                        acc[i][j] = fmaf(avv[i], bvv[j], acc[i][j]);
            }
        }

#pragma unroll
        for (int i = 0; i < 4; ++i) {
            int r = row0 + ty * 4 + i;
            if (r >= M) continue;
#pragma unroll
            for (int j = 0; j < 4; ++j) {
                int cc = col0 + tx * 4 + j;
                if (cc < Nn) C[(long)r * ldc + cc] = acc[i][j];
            }
        }
    } else if (blk < NBsg + NBbc) {
        int b2 = blk - NBsg;
        int nblk = b2 % nbper;
        int cch = b2 / nbper;
        int n = nblk * 256 + tid;
        if (n >= PD) return;
        float s = 0.f;
        if (n < D) {
            int k0 = cch * 8;
            int k1 = k0 + 8; if (k1 > D) k1 = D;
            for (int k = k0; k < k1; ++k) s = fmaf(b_aff[k], B[(long)k * ldb + n], s);
        }
        part[(long)cch * PD + n] = s;
    } else if (blk < NBsg + NBbc + NBv) {
        int k = (blk - NBsg - NBbc) * 4 + (tid >> 6);
        int lane = tid & 63;
        if (k >= 2 * D) return;
        float s = 0.f;
        for (int cc = lane; cc < D; cc += 64) s = fmaf(Win[(long)k * D + cc], wout[cc], s);
#pragma unroll
        for (int m = 32; m > 0; m >>= 1) s += __shfl_down(s, m);
        if (lane == 0) v[k] = s;
    } else {
        float* sm = &As[0][0];
        float s = 0.f;
        for (int cc = tid; cc < D; cc += 256) s = fmaf(b_in[cc], wout[cc], s);
        sm[tid] = s;
        __syncthreads();
        for (int st = 128; st > 0; st >>= 1) {
            if (tid < st) sm[tid] += sm[tid + st];
            __syncthreads();
        }
        if (tid == 0) bdot[0] = sm[0] + b_out[0];
    }
}

// ---------------------------------------------------------------------------
// conv_Bt (+ fused pad): blocks [0,32): Bt[n][k] = bf16(Σ_z Wcp[z][k][n]);
// last blocks: bcp/bgp/v1p/v2p pads.
// ---------------------------------------------------------------------------
__global__ __launch_bounds__(256) void convBt_pad_kernel(
    const float* __restrict__ Wcp, unsigned short* __restrict__ Bt,
    const float* __restrict__ part, const float* __restrict__ b_gcn,
    const float* __restrict__ v, float* __restrict__ bcp,
    float* __restrict__ bgp, float* __restrict__ v1p, float* __restrict__ v2p,
    int D, int PD, int NC, int F, int nConvBlk) {
    const int b = blockIdx.x;
    const int tid = threadIdx.x;
    if (b < nConvBlk) {
        int idx = b * 256 + tid;
        if (idx >= PD * 16) return;
        int n = idx >> 4;
        int k8 = (idx & 15) * 8;
        uint4 o = make_uint4(0, 0, 0, 0);
        if (n < D) {
            unsigned short t[8];
            const long FD = (long)F * D;
#pragma unroll
            for (int q = 0; q < 8; ++q) {
                long off = (long)(k8 + q) * D + n;
                float val = Wcp[off] + Wcp[FD + off] + Wcp[2 * FD + off] + Wcp[3 * FD + off];
                t[q] = f2bf(val);
            }
            o.x = (unsigned)t[0] | ((unsigned)t[1] << 16);
            o.y = (unsigned)t[2] | ((unsigned)t[3] << 16);
            o.z = (unsigned)t[4] | ((unsigned)t[5] << 16);
            o.w = (unsigned)t[6] | ((unsigned)t[7] << 16);
        }
        *reinterpret_cast<uint4*>(Bt + (long)n * 128 + k8) = o;
    } else {
        int i = (b - nConvBlk) * 256 + tid;
        if (i < PD) {
            float s = 0.f;
            for (int c = 0; c < NC; ++c) s += part[(long)c * PD + i];
            bcp[i] = s;
            bgp[i] = (i < D) ? b_gcn[i] : 0.f;
            v1p[i] = (i < D) ? v[i] : 0.f;
            v2p[i] = (i < D) ? v[D + i] : 0.f;
        }
    }
}

// ---------------------------------------------------------------------------
// Feature-space CSR gather, wave per node, 16B/lane loads.
// ---------------------------------------------------------------------------
__global__ __launch_bounds__(256) void gather_feats_kernel(
    const unsigned short* __restrict__ fs16, const int* __restrict__ csr_src,
    const int* __restrict__ row_ptr, const float* __restrict__ ns,
    unsigned short* __restrict__ g16, float* __restrict__ h, int N) {
    int d = blockIdx.x * 4 + (threadIdx.x >> 6);
    int lane = threadIdx.x & 63;
    if (d >= N) return;
    const int g = lane >> 4;      // neighbor slot within quad
    const int fl = lane & 15;     // feature slot (8 feats)

    float a[8] = {0.f, 0.f, 0.f, 0.f, 0.f, 0.f, 0.f, 0.f};
    float hacc = 0.f;

    const int beg = row_ptr[d], end = row_ptr[d + 1];
    for (int j0 = beg; j0 < end; j0 += 64) {
        int cnt = end - j0;
        if (cnt > 64) cnt = 64;
        int s = (lane < cnt) ? csr_src[j0 + lane] : 0;
        if (lane < cnt) hacc += ns[s];
        for (int k = 0; k < cnt; k += 8) {
            int k0 = k + g, k1 = k + 4 + g;
            int i0 = __shfl(s, k0 & 63);
            int i1 = __shfl(s, k1 & 63);
            uint4 v0 = make_uint4(0u, 0u, 0u, 0u), v1 = make_uint4(0u, 0u, 0u, 0u);
            if (k0 < cnt) v0 = *reinterpret_cast<const uint4*>(fs16 + (long)i0 * 128 + fl * 8);
            if (k1 < cnt) v1 = *reinterpret_cast<const uint4*>(fs16 + (long)i1 * 128 + fl * 8);
            a[0] += __uint_as_float(v0.x << 16); a[1] += __uint_as_float(v0.x & 0xFFFF0000u);
            a[2] += __uint_as_float(v0.y << 16); a[3] += __uint_as_float(v0.y & 0xFFFF0000u);
            a[4] += __uint_as_float(v0.z << 16); a[5] += __uint_as_float(v0.z & 0xFFFF0000u);
            a[6] += __uint_as_float(v0.w << 16); a[7] += __uint_as_float(v0.w & 0xFFFF0000u);
            a[0] += __uint_as_float(v1.x << 16); a[1] += __uint_as_float(v1.x & 0xFFFF0000u);
            a[2] += __uint_as_float(v1.y << 16); a[3] += __uint_as_float(v1.y & 0xFFFF0000u);
            a[4] += __uint_as_float(v1.z << 16); a[5] += __uint_as_float(v1.z & 0xFFFF0000u);
            a[6] += __uint_as_float(v1.w << 16); a[7] += __uint_as_float(v1.w & 0xFFFF0000u);
        }
    }

#pragma unroll
    for (int r = 0; r < 8; ++r) {
        a[r] += __shfl_xor(a[r], 16);
        a[r] += __shfl_xor(a[r], 32);
    }
    {
        uint4 sv4 = *reinterpret_cast<const uint4*>(fs16 + (long)d * 128 + fl * 8);
        a[0] += __uint_as_float(sv4.x << 16); a[1] += __uint_as_float(sv4.x & 0xFFFF0000u);
        a[2] += __uint_as_float(sv4.y << 16); a[3] += __uint_as_float(sv4.y & 0xFFFF0000u);
        a[4] += __uint_as_float(sv4.z << 16); a[5] += __uint_as_float(sv4.z & 0xFFFF0000u);
        a[6] += __uint_as_float(sv4.w << 16); a[7] += __uint_as_float(sv4.w & 0xFFFF0000u);
    }
#pragma unroll
    for (int m = 32; m > 0; m >>= 1) hacc += __shfl_xor(hacc, m);
    if (lane == 0) h[d] = hacc + ns[d];
    if (lane < 16) {
        uint4 o;
        o.x = (unsigned)f2bf(a[0]) | ((unsigned)f2bf(a[1]) << 16);
        o.y = (unsigned)f2bf(a[2]) | ((unsigned)f2bf(a[3]) << 16);
        o.z = (unsigned)f2bf(a[4]) | ((unsigned)f2bf(a[5]) << 16);
        o.w = (unsigned)f2bf(a[6]) | ((unsigned)f2bf(a[7]) << 16);
        *reinterpret_cast<uint4*>(g16 + (long)d * 128 + fl * 8) = o;
    }
}

// ---------------------------------------------------------------------------
// MFMA GEMM (R6 geometry, atomic-free u-dots): BM=128 BN=128, grid (GX,4).
// emb[r][c] = nd[r]*( (g16@Wc)[r][c] + h[r]*bcp[c] ) + bgp[c]
// u-dot partials per (colblock by, wavecol) -> plain stores to
// u{1,2}part[(by*2+wc)*Mpad + row]; folded later.
// ---------------------------------------------------------------------------
__global__ __launch_bounds__(256) void gcn_gemm_kernel(
    const unsigned short* __restrict__ g16, const unsigned short* __restrict__ Bt,
    const float* __restrict__ h, const float* __restrict__ nd,
    const float* __restrict__ bcp, const float* __restrict__ bgp,
    const float* __restrict__ v1p, const float* __restrict__ v2p,
    float* __restrict__ emb, float* __restrict__ u1part, float* __restrict__ u2part,
    int M, int D, int Mpad) {

    __shared__ __align__(16) unsigned short As[128 * 32];
    __shared__ __align__(16) unsigned short Bs[128 * 32];

    const int tid  = threadIdx.x;
    const int w    = tid >> 6;
    const int lane = tid & 63;
    const int row0 = blockIdx.x * 128;
    const int col0 = blockIdx.y * 128;

    const int r0   = 2 * w * 16 + (lane >> 2);
    const int r1   = (2 * w + 1) * 16 + (lane >> 2);
    const int slot = lane & 3;
    const int c0   = slot ^ ((r0 >> 1) & 3);
    const int c1   = slot ^ ((r1 >> 1) & 3);

    const unsigned short* pA0 = g16 + (long)(row0 + r0) * 128 + c0 * 8;
    const unsigned short* pA1 = g16 + (long)(row0 + r1) * 128 + c1 * 8;
    const unsigned short* pB0 = Bt + (long)(col0 + r0) * 128 + c0 * 8;
    const unsigned short* pB1 = Bt + (long)(col0 + r1) * 128 + c1 * 8;

    unsigned short* dA0 = As + 2 * w * 512;
    unsigned short* dA1 = As + (2 * w + 1) * 512;
    unsigned short* dB0 = Bs + 2 * w * 512;
    unsigned short* dB1 = Bs + (2 * w + 1) * 512;

    const int wrow = (w & 1) * 64;
    const int wcol = (w >> 1) * 64;
    const int lm = lane & 15, q = lane >> 4;
    const s16x8* pa[4];
    const s16x8* pb[4];
#pragma unroll
    for (int i = 0; i < 4; ++i) {
        int r = wrow + i * 16 + lm;
        int cs = q ^ ((r >> 1) & 3);
        pa[i] = reinterpret_cast<const s16x8*>(As + r * 32 + cs * 8);
        int n = wcol + i * 16 + lm;
        int cs2 = q ^ ((n >> 1) & 3);
        pb[i] = reinterpret_cast<const s16x8*>(Bs + n * 32 + cs2 * 8);
    }

    f32x4 acc[4][4];
#pragma unroll
    for (int i = 0; i < 4; ++i)
#pragma unroll
        for (int j = 0; j < 4; ++j) acc[i][j] = (f32x4)0.f;

    for (int k0 = 0; k0 < 128; k0 += 32) {
        async_ld16(pA0 + k0, dA0);
        async_ld16(pA1 + k0, dA1);
        async_ld16(pB0 + k0, dB0);
        async_ld16(pB1 + k0, dB1);
        __syncthreads();

        s16x8 af[4], bf[4];
#pragma unroll
        for (int i = 0; i < 4; ++i) { af[i] = *pa[i]; bf[i] = *pb[i]; }
#pragma unroll
        for (int i = 0; i < 4; ++i)
#pragma unroll
            for (int j = 0; j < 4; ++j)
                acc[i][j] = __builtin_amdgcn_mfma_f32_16x16x32_bf16(af[i], bf[j], acc[i][j], 0, 0, 0);
        __syncthreads();
    }

    // epilogue: finalize emb + u-dot partials (plain stores, no atomics)
    float bcv[4], bgv[4], w1[4], w2[4];
    int colv[4];
#pragma unroll
    for (int j = 0; j < 4; ++j) {
        int c = col0 + wcol + j * 16 + lm;
        colv[j] = c;
        bcv[j] = bcp[c];
        bgv[j] = bgp[c];
        w1[j] = v1p[c];
        w2[j] = v2p[c];
    }

    const int pb2 = blockIdx.y * 2 + (w >> 1);   // partial slot [0,8)

#pragma unroll
    for (int i = 0; i < 4; ++i) {
        float p1[4], p2[4];
#pragma unroll
        for (int reg = 0; reg < 4; ++reg) {
            int row = row0 + wrow + i * 16 + q * 4 + reg;
            float hb = h[row];
            float sc = (row < M) ? nd[row] : 0.f;
            float s1 = 0.f, s2 = 0.f;
#pragma unroll
            for (int j = 0; j < 4; ++j) {
                float o = fmaf(sc, acc[i][j][reg] + hb * bcv[j], bgv[j]);
                if (row < M && colv[j] < D) emb[(long)row * D + colv[j]] = o;
                s1 = fmaf(o, w1[j], s1);
                s2 = fmaf(o, w2[j], s2);
            }
            p1[reg] = s1;
            p2[reg] = s2;
        }
#pragma unroll
        for (int mask = 1; mask < 16; mask <<= 1)
#pragma unroll
            for (int reg = 0; reg < 4; ++reg) {
                p1[reg] += __shfl_xor(p1[reg], mask);
                p2[reg] += __shfl_xor(p2[reg], mask);
            }
        if (lm == 0) {
#pragma unroll
            for (int reg = 0; reg < 4; ++reg) {
                int row = row0 + wrow + i * 16 + q * 4 + reg;
                u1part[(long)pb2 * Mpad + row] = p1[reg];
                u2part[(long)pb2 * Mpad + row] = p2[reg];
            }
        }
    }
}

// Fold 8 u-dot partials -> u1, u2 (coalesced).
__global__ void ufold_kernel(const float* __restrict__ u1part, const float* __restrict__ u2part,
                             float* __restrict__ u1, float* __restrict__ u2, int N, int Mpad) {
    int i = blockIdx.x * blockDim.x + threadIdx.x;
    if (i < N) {
        float s1 = 0.f, s2 = 0.f;
#pragma unroll
        for (int pb = 0; pb < 8; ++pb) {
            s1 += u1part[(long)pb * Mpad + i];
            s2 += u2part[(long)pb * Mpad + i];
        }
        u1[i] = s1;
        u2[i] = s2;
    }
}

// weights[r] = u1[trip[r,0]] + u2[trip[r,2]] + bias_dot
__global__ void weights_kernel(const int* __restrict__ trip, const float* __restrict__ u1,
                               const float* __restrict__ u2, const float* __restrict__ bdot,
                               float* __restrict__ w, int T) {
    int r = blockIdx.x * blockDim.x + threadIdx.x;
    if (r < T) {
        int s = trip[(long)r * 3 + 0];
        int o = trip[(long)r * 3 + 2];
        w[r] = u1[s] + u2[o] + bdot[0];
    }
}

// ---------------------------------------------------------------------------

extern "C" void kernel_launch(void* const* d_in, const int* in_sizes, int n_in,
                              void* d_out, int out_size, void* d_ws, size_t ws_size,
                              hipStream_t stream) {
    const float* feats      = (const float*)d_in[0];
    const float* W_aff      = (const float*)d_in[1];
    const float* b_aff      = (const float*)d_in[2];
    const float* W_gcn      = (const float*)d_in[3];
    const float* b_gcn      = (const float*)d_in[4];
    const float* W_pred_in  = (const float*)d_in[5];
    const float* b_pred_in  = (const float*)d_in[6];
    const float* W_pred_out = (const float*)d_in[7];
    const float* b_pred_out = (const float*)d_in[8];
    const int*   src        = (const int*)d_in[9];
    const int*   dst        = (const int*)d_in[10];
    const int*   trip       = (const int*)d_in[11];

    const int D = in_sizes[2];           // 500
    const int F = in_sizes[1] / D;       // 128
    const int N = in_sizes[0] / F;       // 50000
    const int E = in_sizes[9];           // 800000
    const int T = in_sizes[11] / 3;      // 200000

    const int PD = 512;
    const int GX = (N + 127) / 128;      // 391 row-blocks
    const int Mpad = GX * 128;           // 50048
    const int NC = (D + 7) / 8;          // bcomb split-K chunks (63)
    const int NBUK = (N >> 8) + 1;       // 196 buckets of 256 nodes
    const int KS = 4;                    // sgemm split-K chunks of 128

    float* weights = (float*)d_out;          // [T]
    float* emb     = (float*)d_out + T;      // [N*D]

    // workspace layout (16B-aligned chunks first)
    char* p = (char*)d_ws;
    unsigned short* fs16 = (unsigned short*)p;  p += (size_t)N * 128 * 2;        // 12.8 MB
    unsigned short* g16  = (unsigned short*)p;  p += (size_t)Mpad * 128 * 2;     // 12.8 MB
    unsigned long long* pairs = (unsigned long long*)p; p += (size_t)E * 8;      // 6.4 MB
    int* ssorted = (int*)p;  p += (size_t)E * 4;                                 // 3.2 MB
    unsigned short* Bt   = (unsigned short*)p;  p += (size_t)PD * 128 * 2;       // 128 KB
    float* Wcp  = (float*)p;  p += (size_t)KS * F * D * 4;                       // 1 MB
    float* bparts = (float*)p;  p += (size_t)64 * PD * 4;                        // 128 KB
    float* bcp  = (float*)p;  p += PD * 4;
    float* bgp  = (float*)p;  p += PD * 4;
    float* v1p  = (float*)p;  p += PD * 4;
    float* v2p  = (float*)p;  p += PD * 4;
    float* v    = (float*)p;  p += 1024 * 4;
    float* bdot = (float*)p;  p += 16;
    float* ns   = (float*)p;  p += (size_t)N * 4;
    float* nd   = (float*)p;  p += (size_t)N * 4;
    float* h    = (float*)p;  p += (size_t)Mpad * 4;
    float* u1   = (float*)p;  p += (size_t)N * 4;
    float* u2   = (float*)p;  p += (size_t)N * 4;
    float* u1part = (float*)p;  p += (size_t)8 * Mpad * 4;                       // 1.6 MB
    float* u2part = (float*)p;  p += (size_t)8 * Mpad * 4;                       // 1.6 MB
    int* bhist_src = (int*)p;  p += 256 * 4;     // bhist_src,bhist_dst contiguous
    int* bhist_dst = (int*)p;  p += 256 * 4;
    int* sbbase   = (int*)p;  p += 260 * 4;
    int* sbcursor = (int*)p;  p += 256 * 4;
    int* dbbase   = (int*)p;  p += 260 * 4;
    int* dbcursor = (int*)p;  p += 256 * 4;
    int* row_ptr = (int*)p;  p += (size_t)(N + 1) * 4;
    int* csr_src = (int*)p;  p += (size_t)E * 4;

    // init: g16 pad rows, h pad, bucket hists
    init_kernel<<<128, 256, 0, stream>>>(
        (unsigned*)(g16 + (size_t)N * 128), (Mpad - N) * 128 / 2,
        h + N, Mpad - N,
        bhist_src, 512);

    // graph prep: histograms -> scans -> fused partition -> finalize(+ns+conv)
    hist2_kernel<<<256, 256, 0, stream>>>(src, dst, bhist_src, bhist_dst, E);
    bscan2_kernel<<<1, 256, 0, stream>>>(bhist_src, bhist_dst, sbbase, sbcursor,
                                         dbbase, dbcursor, NBUK, E);
    fused_partition_kernel<<<(E + PCH - 1) / PCH, 256, 0, stream>>>(
        src, dst, dbcursor, pairs, sbcursor, ssorted, E, NBUK);
    bucket_finalize_kernel<<<NBUK, 256, 0, stream>>>(pairs, dbbase, ssorted, sbbase,
                                                     feats, row_ptr, nd, csr_src, ns,
                                                     fs16, N);

    // dense prep (one launch): sgemm split-K + bcomb partials + vcomb + bias
    {
        const int gxn = (F + 63) / 64;               // 2
        const int gyn = (D + 63) / 64;               // 8
        const int NBsg = gxn * gyn * KS;             // 64
        const int nbper = (PD + 255) / 256;          // 2
        const int NBbc = nbper * NC;                 // 126
        const int NBv = (2 * D + 3) / 4;             // 250
        dense_prep_kernel<<<NBsg + NBbc + NBv + 1, 256, 0, stream>>>(
            W_aff, D, W_gcn, D, Wcp, D, F, D, D,
            b_aff, bparts, W_pred_in, W_pred_out, v,
            b_pred_in, b_pred_out, bdot,
            D, PD, gxn, gyn, NBsg, NBbc, NBv, nbper);
    }
    {
        const int nConvBlk = (PD * 16 + 255) / 256;   // 32
        const int nPadBlk = (PD + 255) / 256;         // 2
        convBt_pad_kernel<<<nConvBlk + nPadBlk, 256, 0, stream>>>(
            Wcp, Bt, bparts, b_gcn, v, bcp, bgp, v1p, v2p, D, PD, NC, F, nConvBlk);
    }

    // feature-space gather: g16, h
    gather_feats_kernel<<<(N + 3) / 4, 256, 0, stream>>>(fs16, csr_src, row_ptr, ns, g16, h, N);

    // MFMA GEMM: emb + u-dot partials (grid (GX,4), no atomics)
    {
        dim3 grid(GX, PD / 128);
        gcn_gemm_kernel<<<grid, 256, 0, stream>>>(g16, Bt, h, nd, bcp, bgp, v1p, v2p,
                                                  emb, u1part, u2part, N, D, Mpad);
    }

    // fold partials -> u1,u2 ; weights from per-node scalars
    ufold_kernel<<<(N + 255) / 256, 256, 0, stream>>>(u1part, u2part, u1, u2, N, Mpad);
    weights_kernel<<<(T + 255) / 256, 256, 0, stream>>>(trip, u1, u2, bdot, weights, T);
}